// Round 2
// baseline (312.629 us; speedup 1.0000x reference)
//
#include <hip/hip_runtime.h>

// AttributeDecoder: gather K*S rows (D=256) from features (N,256), per-head
// Linear 256->8 + bias. fp32.
// R4: locality restructure. R2/R3 showed a hard ~84us wall at 4.8 TB/s of
// L3->L2 gather traffic (402 MB random 1KB rows, 0% L2 hit) -- VALU cuts were
// neutral. This version manufactures L2 locality:
//   Kernel A (24 blocks): per head, counting-sort s by row>>10 into 128
//     1MB position buckets; packed (row<<14)|s lists in workspace.
//   Kernel B (1536 blocks, all resident): block -> XCD slot = blockIdx&7
//     (round-robin dispatch). All blocks of XCD x walk pos = 8t+x, t=0..15,
//     so at any time one XCD's blocks gather from the SAME 1MB row range
//     (+196KB W) -> fits 4MB L2; each range crosses the L2-miss path once.
//   Per-item math = verified R3: XOR-permuted W regs, cndmask-free butterfly.
// Fallback to the verified R3 kernel if ws_size < 1.6 MB.

#define KH 24
#define SS 16384
#define VV 8
#define DD 256
#define NPOS 128            // 1024 rows per bucket = 1 MB of feats

template <int CTRL>
__device__ __forceinline__ float dpp_mov(float x) {
    int xi = __builtin_bit_cast(int, x);
    int r = __builtin_amdgcn_update_dpp(xi, xi, CTRL, 0xF, 0xF, false);
    return __builtin_bit_cast(float, r);
}

// ---------------- Kernel A: per-head bucket sort by row>>10 ----------------
__global__ __launch_bounds__(256) void bucket_kernel(
    const int* __restrict__ mask_idx,   // (24, 16384)
    int* __restrict__ offsets,          // (24, 129)
    unsigned int* __restrict__ list)    // (24, 16384) packed (row<<14)|s
{
    const int head = blockIdx.x;
    const int tid  = threadIdx.x;
    const int* mi = mask_idx + head * SS;

    __shared__ int hist[NPOS];
    __shared__ int base[NPOS];
    __shared__ int cnt[NPOS];
    if (tid < NPOS) { hist[tid] = 0; cnt[tid] = 0; }
    __syncthreads();

    for (int i = tid; i < SS; i += 256)
        atomicAdd(&hist[((unsigned)mi[i]) >> 10], 1);
    __syncthreads();

    if (tid == 0) {
        int a = 0;
        for (int b = 0; b < NPOS; ++b) { base[b] = a; a += hist[b]; }
    }
    __syncthreads();

    if (tid < NPOS) offsets[head * (NPOS + 1) + tid] = base[tid];
    if (tid == 0)   offsets[head * (NPOS + 1) + NPOS] = SS;

    for (int i = tid; i < SS; i += 256) {
        const unsigned row = (unsigned)mi[i];
        const int b = row >> 10;
        const int p = atomicAdd(&cnt[b], 1);
        list[head * SS + base[b] + p] = (row << 14) | (unsigned)i;
    }
}

// ---------------- Kernel B: XCD-phased gather + per-head Linear ------------
__global__ __launch_bounds__(256) void decode_kernel(
    const float* __restrict__ feats,      // (131072, 256)
    const unsigned int* __restrict__ list,
    const int* __restrict__ offsets,
    const float* __restrict__ head_w,     // (24, 256, 8)
    const float* __restrict__ head_b,     // (24, 8)
    float*       __restrict__ out)        // (24, 16384, 8)
{
    const int lane   = threadIdx.x & 63;
    const int wv     = threadIdx.x >> 6;          // 0..3
    const int g      = blockIdx.x;
    const int xcd    = g & 7;                     // dispatch round-robin slot
    const int q      = g >> 3;                    // 0..191
    const int head   = q % KH;
    const int eighth = q / KH;                    // 0..7: slice of the list

    // W slice, per-lane XOR-permuted: w[t][j] = Wk[(lane*4+t)*8 + (j^(lane&7))]
    const float* Wk = head_w + (size_t)head * (DD * VV);
    float w[4][8];
    {
        const bool q0 = (lane & 1) != 0;
        const bool q1 = (lane & 2) != 0;
        const bool q2 = (lane & 4) != 0;
#pragma unroll
        for (int t = 0; t < 4; ++t) {
            const float4 a = *(const float4*)(Wk + (lane * 4 + t) * VV);
            const float4 b = *(const float4*)(Wk + (lane * 4 + t) * VV + 4);
            const float x[8] = {a.x, a.y, a.z, a.w, b.x, b.y, b.z, b.w};
            float y[8], z[8];
#pragma unroll
            for (int j = 0; j < 8; ++j) y[j] = q0 ? x[j ^ 1] : x[j];
#pragma unroll
            for (int j = 0; j < 8; ++j) z[j] = q1 ? y[j ^ 2] : y[j];
#pragma unroll
            for (int j = 0; j < 8; ++j) w[t][j] = q2 ? z[j ^ 4] : z[j];
        }
    }
    const float bias = head_b[head * VV + (lane & 7)];

    const char* fb = (const char*)feats;
    const int vo = lane << 4;
    const unsigned int* lst = list + head * SS;
    const int* offs = offsets + head * (NPOS + 1);
    float* outh = out + (size_t)head * SS * VV;
    const int widx = eighth * 4 + wv;             // 0..31: wave slot in pos list

    for (int t = 0; t < 16; ++t) {
        const int pos = t * 8 + xcd;              // pos % 8 == xcd always
        const int lo = offs[pos];
        const int hi = offs[pos + 1];
        int j = lo + widx;
        if (j >= hi) continue;

        unsigned e0 = lst[j];                     // wave-uniform
        int r0 = __builtin_amdgcn_readfirstlane((int)(e0 >> 14));
        float4 f0 = *(const float4*)(fb + (((size_t)(unsigned)r0) << 10) + vo);

        for (; j < hi; j += 32) {
            const int jn = j + 32;
            unsigned e1 = e0;
            float4 f1 = f0;
            if (jn < hi) {                        // 1-deep pipeline: next gather
                e1 = lst[jn];                     //   in flight during compute
                int r1 = __builtin_amdgcn_readfirstlane((int)(e1 >> 14));
                f1 = *(const float4*)(fb + (((size_t)(unsigned)r1) << 10) + vo);
            }

            float acc[8];
#pragma unroll
            for (int v = 0; v < 8; ++v) {
                acc[v] = f0.x * w[0][v];
                acc[v] = fmaf(f0.y, w[1][v], acc[v]);
                acc[v] = fmaf(f0.z, w[2][v], acc[v]);
                acc[v] = fmaf(f0.w, w[3][v], acc[v]);
            }
            // cndmask-free split-butterfly (w pre-permuted): after xor1/2/4
            // lane holds v=lane&7 over its 8-lane cluster; then plain xor8/16/32.
            const float a40 = acc[0] + dpp_mov<0xB1>(acc[1]);
            const float a41 = acc[2] + dpp_mov<0xB1>(acc[3]);
            const float a42 = acc[4] + dpp_mov<0xB1>(acc[5]);
            const float a43 = acc[6] + dpp_mov<0xB1>(acc[7]);
            const float a20 = a40 + dpp_mov<0x4E>(a41);
            const float a21 = a42 + dpp_mov<0x4E>(a43);
            float va = a20 + __shfl_xor(a21, 4, 64);
            va += dpp_mov<0x128>(va);             // row_ror:8 == xor8
            va += __shfl_xor(va, 16, 64);
            va += __shfl_xor(va, 32, 64);

            const int s = (int)(e0 & 16383u);
            if (lane < 8) outh[(size_t)s * VV + lane] = va + bias;

            e0 = e1; f0 = f1;
        }
    }
}

// ---------------- Fallback (verified R3) if workspace too small ------------
__global__ __launch_bounds__(256) void attr_decoder_fallback(
    const float* __restrict__ feats, const int* __restrict__ mask_idx,
    const float* __restrict__ head_w, const float* __restrict__ head_b,
    float* __restrict__ out)
{
    const int lane  = threadIdx.x & 63;
    const int wv    = __builtin_amdgcn_readfirstlane(threadIdx.x >> 6);
    const int k     = blockIdx.x >> 7;
    const int chunk = blockIdx.x & 127;
    const int lb    = lane & 7;

    const float* Wk = head_w + (size_t)k * (DD * VV);
    float w[4][8];
    {
        const bool q0 = (lane & 1) != 0;
        const bool q1 = (lane & 2) != 0;
        const bool q2 = (lane & 4) != 0;
#pragma unroll
        for (int t = 0; t < 4; ++t) {
            const float4 a = *(const float4*)(Wk + (lane * 4 + t) * VV);
            const float4 b = *(const float4*)(Wk + (lane * 4 + t) * VV + 4);
            const float x[8] = {a.x, a.y, a.z, a.w, b.x, b.y, b.z, b.w};
            float y[8], z[8];
#pragma unroll
            for (int j = 0; j < 8; ++j) y[j] = q0 ? x[j ^ 1] : x[j];
#pragma unroll
            for (int j = 0; j < 8; ++j) z[j] = q1 ? y[j ^ 2] : y[j];
#pragma unroll
            for (int j = 0; j < 8; ++j) w[t][j] = q2 ? z[j ^ 4] : z[j];
        }
    }
    const float bias = head_b[k * VV + lb];

    const char* fb = (const char*)feats;
    const int s_base = chunk * 128 + wv * 32;
    const int* mi = mask_idx + k * SS + s_base;
    float* outp = out + ((size_t)k * SS + s_base) * VV;
    const int vo = lane << 4;

    int4 rows = *(const int4*)mi;
    int r0 = __builtin_amdgcn_readfirstlane(rows.x);
    int r1 = __builtin_amdgcn_readfirstlane(rows.y);
    int r2 = __builtin_amdgcn_readfirstlane(rows.z);
    int r3 = __builtin_amdgcn_readfirstlane(rows.w);

    for (int i = 0; i < 32; i += 4) {
        const float4 f0 = *(const float4*)(fb + (((size_t)(unsigned)r0) << 10) + vo);
        const float4 f1 = *(const float4*)(fb + (((size_t)(unsigned)r1) << 10) + vo);
        const float4 f2 = *(const float4*)(fb + (((size_t)(unsigned)r2) << 10) + vo);
        const float4 f3 = *(const float4*)(fb + (((size_t)(unsigned)r3) << 10) + vo);
        if (i < 28) rows = *(const int4*)(mi + i + 4);

        float r[4];
        const float4 f[4] = {f0, f1, f2, f3};
#pragma unroll
        for (int u = 0; u < 4; ++u) {
            float acc[8];
#pragma unroll
            for (int v = 0; v < 8; ++v) {
                acc[v] = f[u].x * w[0][v];
                acc[v] = fmaf(f[u].y, w[1][v], acc[v]);
                acc[v] = fmaf(f[u].z, w[2][v], acc[v]);
                acc[v] = fmaf(f[u].w, w[3][v], acc[v]);
            }
            const float a40 = acc[0] + dpp_mov<0xB1>(acc[1]);
            const float a41 = acc[2] + dpp_mov<0xB1>(acc[3]);
            const float a42 = acc[4] + dpp_mov<0xB1>(acc[5]);
            const float a43 = acc[6] + dpp_mov<0xB1>(acc[7]);
            const float a20 = a40 + dpp_mov<0x4E>(a41);
            const float a21 = a42 + dpp_mov<0x4E>(a43);
            r[u] = a20 + __shfl_xor(a21, 4, 64);
        }
        r0 = __builtin_amdgcn_readfirstlane(rows.x);
        r1 = __builtin_amdgcn_readfirstlane(rows.y);
        r2 = __builtin_amdgcn_readfirstlane(rows.z);
        r3 = __builtin_amdgcn_readfirstlane(rows.w);

        const bool b3 = (lane & 8) != 0;
        const bool b4 = (lane & 16) != 0;
        const float t0 = (b3 ? r[1] : r[0]) + dpp_mov<0x128>(b3 ? r[0] : r[1]);
        const float t1 = (b3 ? r[3] : r[2]) + dpp_mov<0x128>(b3 ? r[2] : r[3]);
        float va = (b4 ? t1 : t0) + __shfl_xor(b4 ? t0 : t1, 16, 64);
        va += __shfl_xor(va, 32, 64);
        if (lane < 32) outp[i * VV + lane] = va + bias;
    }
}

extern "C" void kernel_launch(void* const* d_in, const int* in_sizes, int n_in,
                              void* d_out, int out_size, void* d_ws, size_t ws_size,
                              hipStream_t stream) {
    const float* feats    = (const float*)d_in[1];
    const int*   mask_idx = (const int*)  d_in[2];
    const float* head_w   = (const float*)d_in[3];
    const float* head_b   = (const float*)d_in[4];
    float* out = (float*)d_out;

    const size_t need = 16384 + (size_t)KH * SS * 4;   // offsets pad + lists
    if (d_ws != nullptr && ws_size >= need) {
        int* offsets = (int*)d_ws;
        unsigned int* list = (unsigned int*)((char*)d_ws + 16384);
        bucket_kernel<<<dim3(KH), dim3(256), 0, stream>>>(mask_idx, offsets, list);
        decode_kernel<<<dim3(1536), dim3(256), 0, stream>>>(
            feats, list, offsets, head_w, head_b, out);
    } else {
        attr_decoder_fallback<<<dim3(KH * 128), dim3(256), 0, stream>>>(
            feats, mask_idx, head_w, head_b, out);
    }
}

// Round 3
// 268.876 us; speedup vs baseline: 1.1627x; 1.1627x over previous
//
#include <hip/hip_runtime.h>

// AttributeDecoder: gather K*S rows (D=256) from features (N,256), per-head
// Linear 256->8 + bias. fp32.
// R5: bucketed-locality (R4) + high-MLP group engine (R3).
//  R4 post-mortem: FETCH 193->64MB (time-coherent windows work) but decode
//  83.5->120.9us: 1-item/iter pipeline starved the gather pipe (3.3 vs 4.8
//  TB/s). Fix: per (head,xcd) the list is ONE contiguous 16B-aligned
//  zero-padded segment (buckets b==xcd mod 8 ordered by t=b>>3), so decode
//  runs the verified R3 loop: 4-item groups, one aligned int4 list load,
//  4 saddr gathers in flight, next-group indices prefetched under compute.
//  All 32 waves of a (head,xcd) stride the same 128-item/1MB window in
//  lockstep -> per-XCD L2 reuse (blockIdx&7 -> XCD round-robin).
// Fallback to the verified R3 kernel if ws_size too small.

#define KH 24
#define SS 16384
#define VV 8
#define DD 256
#define NPOS 128            // 1024 rows per bucket = 1 MB of feats
#define SEG_CAP 16416       // per-head padded list capacity (16384 + 8*4)

template <int CTRL>
__device__ __forceinline__ float dpp_mov(float x) {
    int xi = __builtin_bit_cast(int, x);
    int r = __builtin_amdgcn_update_dpp(xi, xi, CTRL, 0xF, 0xF, false);
    return __builtin_bit_cast(float, r);
}

// ---- Kernel A: per-head counting sort into xcd-permuted padded segments ----
__global__ __launch_bounds__(256) void bucket_kernel(
    const int* __restrict__ mask_idx,   // (24, 16384)
    int2* __restrict__ bounds,          // (24, 8) {lo, hi} item indices
    unsigned int* __restrict__ list)    // (24, SEG_CAP) packed (row<<14)|s
{
    const int head = blockIdx.x;
    const int tid  = threadIdx.x;
    const int* mi = mask_idx + head * SS;
    unsigned int* lh = list + head * SEG_CAP;

    __shared__ int hist[NPOS];
    __shared__ int cnt[NPOS];
    __shared__ int bbase[NPOS];
    __shared__ int seglo[8], seghi[8];

    if (tid < NPOS) { hist[tid] = 0; cnt[tid] = 0; }
    __syncthreads();

    for (int i = tid; i < SS; i += 256)
        atomicAdd(&hist[((unsigned)mi[i]) >> 10], 1);
    __syncthreads();

    if (tid == 0) {
        int a = 0;
        for (int x = 0; x < 8; ++x) {
            seglo[x] = a;
            for (int t = 0; t < 16; ++t) {     // buckets b = x + 8t, t-ordered
                bbase[x + 8 * t] = a;
                a += hist[x + 8 * t];
            }
            seghi[x] = a;
            a = (a + 3) & ~3;                  // 16B-align next segment
        }
    }
    __syncthreads();

    if (tid < 8) {
        bounds[head * 8 + tid] = make_int2(seglo[tid], seghi[tid]);
        for (int p = seghi[tid]; p < ((seghi[tid] + 3) & ~3); ++p)
            lh[p] = 0u;                        // harmless pad: row 0, s 0
    }

    for (int i = tid; i < SS; i += 256) {
        const unsigned row = (unsigned)mi[i];
        const int b = row >> 10;
        const int p = atomicAdd(&cnt[b], 1);
        lh[bbase[b] + p] = (row << 14) | (unsigned)i;
    }
}

// ---- Kernel B: XCD-phased gather + per-head Linear, R3 group engine -------
__global__ __launch_bounds__(256) void decode_kernel(
    const float* __restrict__ feats,      // (131072, 256)
    const unsigned int* __restrict__ list,
    const int2* __restrict__ bounds,
    const float* __restrict__ head_w,     // (24, 256, 8)
    const float* __restrict__ head_b,     // (24, 8)
    float*       __restrict__ out)        // (24, 16384, 8)
{
    const int lane   = threadIdx.x & 63;
    const int wv     = threadIdx.x >> 6;          // 0..3
    const int gid    = blockIdx.x;
    const int xcd    = gid & 7;                   // dispatch round-robin slot
    const int q      = gid >> 3;                  // 0..191
    const int head   = q % KH;
    const int eighth = q / KH;                    // 0..7
    const int widx   = eighth * 4 + wv;           // 0..31 wave slot

    // W slice, per-lane XOR-permuted: w[t][j] = Wk[(lane*4+t)*8 + (j^(lane&7))]
    const float* Wk = head_w + (size_t)head * (DD * VV);
    float w[4][8];
    {
        const bool q0 = (lane & 1) != 0;
        const bool q1 = (lane & 2) != 0;
        const bool q2 = (lane & 4) != 0;
#pragma unroll
        for (int t = 0; t < 4; ++t) {
            const float4 a = *(const float4*)(Wk + (lane * 4 + t) * VV);
            const float4 b = *(const float4*)(Wk + (lane * 4 + t) * VV + 4);
            const float x[8] = {a.x, a.y, a.z, a.w, b.x, b.y, b.z, b.w};
            float y[8], z[8];
#pragma unroll
            for (int j = 0; j < 8; ++j) y[j] = q0 ? x[j ^ 1] : x[j];
#pragma unroll
            for (int j = 0; j < 8; ++j) z[j] = q1 ? y[j ^ 2] : y[j];
#pragma unroll
            for (int j = 0; j < 8; ++j) w[t][j] = q2 ? z[j ^ 4] : z[j];
        }
    }
    const float bias = head_b[head * VV + (lane & 7)];

    const int2 bd = bounds[head * 8 + xcd];
    const int lo = bd.x, hi = bd.y;
    const unsigned int* lst = list + (size_t)head * SEG_CAP;
    const char* fb = (const char*)feats;
    const int vo = lane << 4;
    float* outh = out + (size_t)head * SS * VV;

    int base = lo + widx * 4;                     // 16B-aligned (lo 4-aligned)
    if (base >= hi) return;

    int4 ee = *(const int4*)(lst + base);
    int r0 = __builtin_amdgcn_readfirstlane((int)(((unsigned)ee.x) >> 14));
    int r1 = __builtin_amdgcn_readfirstlane((int)(((unsigned)ee.y) >> 14));
    int r2 = __builtin_amdgcn_readfirstlane((int)(((unsigned)ee.z) >> 14));
    int r3 = __builtin_amdgcn_readfirstlane((int)(((unsigned)ee.w) >> 14));

    for (; base < hi; base += 128) {
        const unsigned e0 = (unsigned)ee.x, e1 = (unsigned)ee.y;
        const unsigned e2 = (unsigned)ee.z, e3 = (unsigned)ee.w;

        // 4 gathers in flight, scalar bases (saddr), zero VALU addr math.
        const float4 f0 = *(const float4*)(fb + (((size_t)(unsigned)r0) << 10) + vo);
        const float4 f1 = *(const float4*)(fb + (((size_t)(unsigned)r1) << 10) + vo);
        const float4 f2 = *(const float4*)(fb + (((size_t)(unsigned)r2) << 10) + vo);
        const float4 f3 = *(const float4*)(fb + (((size_t)(unsigned)r3) << 10) + vo);

        int4 een = ee;
        if (base + 128 < hi) een = *(const int4*)(lst + base + 128);  // prefetch

        float r[4];
        const float4 f[4] = {f0, f1, f2, f3};
#pragma unroll
        for (int u = 0; u < 4; ++u) {
            float acc[8];
#pragma unroll
            for (int v = 0; v < 8; ++v) {
                acc[v] = f[u].x * w[0][v];
                acc[v] = fmaf(f[u].y, w[1][v], acc[v]);
                acc[v] = fmaf(f[u].z, w[2][v], acc[v]);
                acc[v] = fmaf(f[u].w, w[3][v], acc[v]);
            }
            // cndmask-free split-butterfly (w pre-permuted): after xor1/2/4
            // lane holds v=lane&7 over its 8-lane cluster.
            const float a40 = acc[0] + dpp_mov<0xB1>(acc[1]);
            const float a41 = acc[2] + dpp_mov<0xB1>(acc[3]);
            const float a42 = acc[4] + dpp_mov<0xB1>(acc[5]);
            const float a43 = acc[6] + dpp_mov<0xB1>(acc[7]);
            const float a20 = a40 + dpp_mov<0x4E>(a41);
            const float a21 = a42 + dpp_mov<0x4E>(a43);
            r[u] = a20 + __shfl_xor(a21, 4, 64);
        }

        r0 = __builtin_amdgcn_readfirstlane((int)(((unsigned)een.x) >> 14));
        r1 = __builtin_amdgcn_readfirstlane((int)(((unsigned)een.y) >> 14));
        r2 = __builtin_amdgcn_readfirstlane((int)(((unsigned)een.z) >> 14));
        r3 = __builtin_amdgcn_readfirstlane((int)(((unsigned)een.w) >> 14));

        // s-split tail (R3, verified): lane l<32 ends holding item u=l>>3,
        // v=l&7.
        const bool b3 = (lane & 8) != 0;
        const bool b4 = (lane & 16) != 0;
        const float t0 = (b3 ? r[1] : r[0]) + dpp_mov<0x128>(b3 ? r[0] : r[1]);
        const float t1 = (b3 ? r[3] : r[2]) + dpp_mov<0x128>(b3 ? r[2] : r[3]);
        float va = (b4 ? t1 : t0) + __shfl_xor(b4 ? t0 : t1, 16, 64);
        va += __shfl_xor(va, 32, 64);

        const int u = (lane >> 3) & 3;
        const unsigned eu = b4 ? (b3 ? e3 : e2) : (b3 ? e1 : e0);
        const int s = (int)(eu & 16383u);
        if (lane < 32 && base + u < hi)
            outh[(size_t)s * VV + (lane & 7)] = va + bias;

        ee = een;
    }
}

// ---------------- Fallback (verified R3) if workspace too small ------------
__global__ __launch_bounds__(256) void attr_decoder_fallback(
    const float* __restrict__ feats, const int* __restrict__ mask_idx,
    const float* __restrict__ head_w, const float* __restrict__ head_b,
    float* __restrict__ out)
{
    const int lane  = threadIdx.x & 63;
    const int wv    = __builtin_amdgcn_readfirstlane(threadIdx.x >> 6);
    const int k     = blockIdx.x >> 7;
    const int chunk = blockIdx.x & 127;
    const int lb    = lane & 7;

    const float* Wk = head_w + (size_t)k * (DD * VV);
    float w[4][8];
    {
        const bool q0 = (lane & 1) != 0;
        const bool q1 = (lane & 2) != 0;
        const bool q2 = (lane & 4) != 0;
#pragma unroll
        for (int t = 0; t < 4; ++t) {
            const float4 a = *(const float4*)(Wk + (lane * 4 + t) * VV);
            const float4 b = *(const float4*)(Wk + (lane * 4 + t) * VV + 4);
            const float x[8] = {a.x, a.y, a.z, a.w, b.x, b.y, b.z, b.w};
            float y[8], z[8];
#pragma unroll
            for (int j = 0; j < 8; ++j) y[j] = q0 ? x[j ^ 1] : x[j];
#pragma unroll
            for (int j = 0; j < 8; ++j) z[j] = q1 ? y[j ^ 2] : y[j];
#pragma unroll
            for (int j = 0; j < 8; ++j) w[t][j] = q2 ? z[j ^ 4] : z[j];
        }
    }
    const float bias = head_b[k * VV + lb];

    const char* fb = (const char*)feats;
    const int s_base = chunk * 128 + wv * 32;
    const int* mi = mask_idx + k * SS + s_base;
    float* outp = out + ((size_t)k * SS + s_base) * VV;
    const int vo = lane << 4;

    int4 rows = *(const int4*)mi;
    int r0 = __builtin_amdgcn_readfirstlane(rows.x);
    int r1 = __builtin_amdgcn_readfirstlane(rows.y);
    int r2 = __builtin_amdgcn_readfirstlane(rows.z);
    int r3 = __builtin_amdgcn_readfirstlane(rows.w);

    for (int i = 0; i < 32; i += 4) {
        const float4 f0 = *(const float4*)(fb + (((size_t)(unsigned)r0) << 10) + vo);
        const float4 f1 = *(const float4*)(fb + (((size_t)(unsigned)r1) << 10) + vo);
        const float4 f2 = *(const float4*)(fb + (((size_t)(unsigned)r2) << 10) + vo);
        const float4 f3 = *(const float4*)(fb + (((size_t)(unsigned)r3) << 10) + vo);
        if (i < 28) rows = *(const int4*)(mi + i + 4);

        float r[4];
        const float4 f[4] = {f0, f1, f2, f3};
#pragma unroll
        for (int u = 0; u < 4; ++u) {
            float acc[8];
#pragma unroll
            for (int v = 0; v < 8; ++v) {
                acc[v] = f[u].x * w[0][v];
                acc[v] = fmaf(f[u].y, w[1][v], acc[v]);
                acc[v] = fmaf(f[u].z, w[2][v], acc[v]);
                acc[v] = fmaf(f[u].w, w[3][v], acc[v]);
            }
            const float a40 = acc[0] + dpp_mov<0xB1>(acc[1]);
            const float a41 = acc[2] + dpp_mov<0xB1>(acc[3]);
            const float a42 = acc[4] + dpp_mov<0xB1>(acc[5]);
            const float a43 = acc[6] + dpp_mov<0xB1>(acc[7]);
            const float a20 = a40 + dpp_mov<0x4E>(a41);
            const float a21 = a42 + dpp_mov<0x4E>(a43);
            r[u] = a20 + __shfl_xor(a21, 4, 64);
        }
        r0 = __builtin_amdgcn_readfirstlane(rows.x);
        r1 = __builtin_amdgcn_readfirstlane(rows.y);
        r2 = __builtin_amdgcn_readfirstlane(rows.z);
        r3 = __builtin_amdgcn_readfirstlane(rows.w);

        const bool b3 = (lane & 8) != 0;
        const bool b4 = (lane & 16) != 0;
        const float t0 = (b3 ? r[1] : r[0]) + dpp_mov<0x128>(b3 ? r[0] : r[1]);
        const float t1 = (b3 ? r[3] : r[2]) + dpp_mov<0x128>(b3 ? r[2] : r[3]);
        float va = (b4 ? t1 : t0) + __shfl_xor(b4 ? t0 : t1, 16, 64);
        va += __shfl_xor(va, 32, 64);
        if (lane < 32) outp[i * VV + lane] = va + bias;
    }
}

extern "C" void kernel_launch(void* const* d_in, const int* in_sizes, int n_in,
                              void* d_out, int out_size, void* d_ws, size_t ws_size,
                              hipStream_t stream) {
    const float* feats    = (const float*)d_in[1];
    const int*   mask_idx = (const int*)  d_in[2];
    const float* head_w   = (const float*)d_in[3];
    const float* head_b   = (const float*)d_in[4];
    float* out = (float*)d_out;

    const size_t need = 4096 + (size_t)KH * SEG_CAP * 4;   // bounds + lists
    if (d_ws != nullptr && ws_size >= need) {
        int2* bounds = (int2*)d_ws;
        unsigned int* list = (unsigned int*)((char*)d_ws + 4096);
        bucket_kernel<<<dim3(KH), dim3(256), 0, stream>>>(mask_idx, bounds, list);
        decode_kernel<<<dim3(1536), dim3(256), 0, stream>>>(
            feats, list, bounds, head_w, head_b, out);
    } else {
        attr_decoder_fallback<<<dim3(KH * 128), dim3(256), 0, stream>>>(
            feats, mask_idx, head_w, head_b, out);
    }
}